// Round 6
// baseline (50.793 us; speedup 1.0000x reference)
//
#include <hip/hip_runtime.h>
#include <hip/hip_bf16.h>

#define NROWS 4096
#define DIM   1024
#define BT    256            // tile edge (256x256 per block)
#define BK    64             // K-step
#define NKT   (DIM / BK)     // 16 K-steps
#define NTB   (NROWS / BT)   // 16 tile-blocks per edge
#define TEMP_INV 10.0f

typedef __bf16 bf16x8 __attribute__((ext_vector_type(8)));
typedef float  f32x4  __attribute__((ext_vector_type(4)));

__device__ __forceinline__ void gload16(const void* g, void* l) {
    __builtin_amdgcn_global_load_lds(
        (const __attribute__((address_space(1))) void*)g,
        (__attribute__((address_space(3))) void*)l, 16, 0, 0);
}

__device__ __forceinline__ unsigned short f2bf(float f) {
    __hip_bfloat16 h = __float2bfloat16(f);
    return *reinterpret_cast<unsigned short*>(&h);
}

// Stage one 64-row chunk (8 KB) of a 256x64 K-tile: 1 gload16/thread.
// Linear LDS dest (m104); bank swizzle kg ^= r&7 applied by pre-swizzling the
// global source granule (rule 21: source perm == read perm; 0 conflicts @R4).
__device__ __forceinline__ void stage_chunk(const unsigned short* __restrict__ src,
                                            unsigned short* lds, int tid, int c) {
    const int p  = c * 512 + tid;        // granule (16B units)
    const int r  = p >> 3;               // tile row (8 granules = 128B/row)
    const int kg = (p & 7) ^ (r & 7);    // logical k-granule held at p
    gload16(src + (size_t)r * DIM + kg * 8, lds + p * 8);
}

// Row-normalize fp32 -> bf16; zeroes this row's partial accumulators.
__global__ __launch_bounds__(256) void normalize_k(const float* __restrict__ pred,
                                                   unsigned short* __restrict__ xn,
                                                   float* __restrict__ posw,
                                                   float* __restrict__ denw) {
    const int row = blockIdx.x;
    const int tid = threadIdx.x;
    const float4 v = reinterpret_cast<const float4*>(pred + (size_t)row * DIM)[tid];
    float ss = v.x * v.x + v.y * v.y + v.z * v.z + v.w * v.w;
    #pragma unroll
    for (int off = 32; off; off >>= 1) ss += __shfl_xor(ss, off, 64);
    __shared__ float red[4];
    if ((tid & 63) == 0) red[tid >> 6] = ss;
    __syncthreads();
    const float tot = red[0] + red[1] + red[2] + red[3];
    const float scale = 1.0f / fmaxf(sqrtf(tot), 1e-8f);
    ushort4 o;
    o.x = f2bf(v.x * scale);
    o.y = f2bf(v.y * scale);
    o.z = f2bf(v.z * scale);
    o.w = f2bf(v.w * scale);
    reinterpret_cast<ushort4*>(xn + (size_t)row * DIM)[tid] = o;
    if (tid == 0) { posw[row] = 0.0f; denw[row] = 0.0f; }
}

#define BAR asm volatile("s_barrier" ::: "memory")
#define WAITV2 asm volatile("s_waitcnt vmcnt(2)" ::: "memory")
#define WAITV0 asm volatile("s_waitcnt vmcnt(0)" ::: "memory")

// Fused Gram-GEMM + contrastive epilogue.  Full 16x16 grid (256 blocks, 1/CU),
// 8 waves (2M x 4N), per-wave output 128x64.  m201-style 4-phase K-step:
// each phase {ds_read subtile | stage 2 chunks -> BAR -> prio1 16 MFMA prio0
// -> [counted vmcnt] BAR}.  Stage order {B0,B1|B2,B3|A0,A2|A1,A3} makes the
// two vmcnt(2) waits (end-ph1, end-ph4) drain exactly what the next phase
// needs; loads never drain to 0 inside the loop (T4).
__global__ __launch_bounds__(512, 2) void fused_gram(
        const unsigned short* __restrict__ xn, const int* __restrict__ tgt,
        float* __restrict__ posw, float* __restrict__ denw) {
    __shared__ unsigned short As[2][BT * BK];   // 2 x 32 KB
    __shared__ unsigned short Bs[2][BT * BK];   // 2 x 32 KB  (128 KB total)

    const int bi = blockIdx.x >> 4;
    const int bj = blockIdx.x & 15;
    const int rowbase = bi * BT;
    const int colbase = bj * BT;

    const int tid = threadIdx.x;
    const int w   = tid >> 6;
    const int l   = tid & 63;
    const int wr  = w >> 2;      // 0..1  (row half: 128 rows)
    const int wc  = w & 3;       // 0..3  (col quarter: 64 cols)
    const int l15 = l & 15;
    const int kgl = l >> 4;      // 0..3

    const unsigned short* arow = xn + (size_t)rowbase * DIM;
    const unsigned short* bcol = xn + (size_t)colbase * DIM;

    // Hoisted LDS element offsets.  Read granule for k-slice ks is
    // (ks*4 + kgl) ^ (lr & 7)  (lr & 7 == l15 & 7 since wr/fi terms are x16).
    int baseA[8], baseB[4];
    #pragma unroll
    for (int fi = 0; fi < 8; ++fi) baseA[fi] = (wr * 128 + fi * 16 + l15) * 64;
    #pragma unroll
    for (int fj = 0; fj < 4; ++fj) baseB[fj] = (wc * 64 + fj * 16 + l15) * 64;
    const int x0 = ((0 + kgl) ^ (l15 & 7)) * 8;
    const int x1 = ((4 + kgl) ^ (l15 & 7)) * 8;

    f32x4 acc[8][4];
    #pragma unroll
    for (int i = 0; i < 8; ++i)
        #pragma unroll
        for (int j = 0; j < 4; ++j)
            acc[i][j] = (f32x4){0.f, 0.f, 0.f, 0.f};

    // Prologue: stage tile 0 in wait-ledger order B0,B1,B2,B3,A0,A2,A1,A3.
    stage_chunk(bcol, &Bs[0][0], tid, 0);
    stage_chunk(bcol, &Bs[0][0], tid, 1);
    stage_chunk(bcol, &Bs[0][0], tid, 2);
    stage_chunk(bcol, &Bs[0][0], tid, 3);
    stage_chunk(arow, &As[0][0], tid, 0);
    stage_chunk(arow, &As[0][0], tid, 2);
    stage_chunk(arow, &As[0][0], tid, 1);
    stage_chunk(arow, &As[0][0], tid, 3);
    WAITV2;          // B0-3, A0, A2 landed; A1, A3 carried (drained end-ph1)
    BAR;

#define MFMA_HALF(AF, FI0)                                                     \
    do {                                                                       \
        __builtin_amdgcn_s_setprio(1);                                         \
        _Pragma("unroll")                                                      \
        for (int fi_ = 0; fi_ < 4; ++fi_)                                      \
            _Pragma("unroll")                                                  \
            for (int fj_ = 0; fj_ < 4; ++fj_)                                  \
                acc[FI0 + fi_][fj_] = __builtin_amdgcn_mfma_f32_16x16x32_bf16( \
                    AF[fi_], bb[fj_], acc[FI0 + fi_][fj_], 0, 0, 0);           \
        __builtin_amdgcn_s_setprio(0);                                         \
    } while (0)

    for (int kt = 0; kt < NKT; ++kt) {
        const int cur = kt & 1;
        const unsigned short* as = &As[cur][0];
        const unsigned short* bs = &Bs[cur][0];
        unsigned short* an = &As[cur ^ 1][0];
        unsigned short* bn = &Bs[cur ^ 1][0];
        const unsigned short* ag = arow + (kt + 1) * BK;
        const unsigned short* bg = bcol + (kt + 1) * BK;
        const bool st = (kt + 1 < NKT);
        bf16x8 aL[4], aH[4], bb[4];

        // ---- phase 1: (ks0, fi 0-3): 8 ds_read + stage B0,B1 ----
        #pragma unroll
        for (int fi = 0; fi < 4; ++fi)
            aL[fi] = *reinterpret_cast<const bf16x8*>(&as[baseA[fi] + x0]);
        #pragma unroll
        for (int fj = 0; fj < 4; ++fj)
            bb[fj] = *reinterpret_cast<const bf16x8*>(&bs[baseB[fj] + x0]);
        if (st) { stage_chunk(bg, bn, tid, 0); stage_chunk(bg, bn, tid, 1); }
        BAR;
        MFMA_HALF(aL, 0);
        if (kt == NKT - 1) { WAITV0; } else { WAITV2; }   // drain carry A1,A3
        BAR;

        // ---- phase 2: (ks0, fi 4-7): 4 ds_read + stage B2,B3 ----
        #pragma unroll
        for (int fi = 0; fi < 4; ++fi)
            aH[fi] = *reinterpret_cast<const bf16x8*>(&as[baseA[4 + fi] + x0]);
        if (st) { stage_chunk(bg, bn, tid, 2); stage_chunk(bg, bn, tid, 3); }
        BAR;
        MFMA_HALF(aH, 4);
        BAR;

        // ---- phase 3: (ks1, fi 0-3): 8 ds_read + stage A0,A2 ----
        #pragma unroll
        for (int fi = 0; fi < 4; ++fi)
            aL[fi] = *reinterpret_cast<const bf16x8*>(&as[baseA[fi] + x1]);
        #pragma unroll
        for (int fj = 0; fj < 4; ++fj)
            bb[fj] = *reinterpret_cast<const bf16x8*>(&bs[baseB[fj] + x1]);
        if (st) { stage_chunk(ag, an, tid, 0); stage_chunk(ag, an, tid, 2); }
        BAR;
        MFMA_HALF(aL, 0);
        BAR;

        // ---- phase 4: (ks1, fi 4-7): 4 ds_read + stage A1,A3 ----
        #pragma unroll
        for (int fi = 0; fi < 4; ++fi)
            aH[fi] = *reinterpret_cast<const bf16x8*>(&as[baseA[4 + fi] + x1]);
        if (st) { stage_chunk(ag, an, tid, 1); stage_chunk(ag, an, tid, 3); }
        BAR;
        MFMA_HALF(aH, 4);
        if (st) { WAITV2; }   // B0-3 + A0,A2 of tile kt+1 landed; A1,A3 carry
        BAR;
    }
#undef MFMA_HALF

    // Fused epilogue (column-side only; full grid covers both (i,j),(j,i)).
    // C/D layout: col = lane&15, row = (lane>>4)*4 + q  [m89/m91, verified]
    int jc[4], tj[4];
    #pragma unroll
    for (int fj = 0; fj < 4; ++fj) {
        jc[fj] = colbase + wc * 64 + fj * 16 + l15;
        tj[fj] = tgt[jc[fj]];
    }
    float denc[4] = {0.f, 0.f, 0.f, 0.f};
    float posc[4] = {0.f, 0.f, 0.f, 0.f};

    #pragma unroll
    for (int fi = 0; fi < 8; ++fi) {
        const int ribase = rowbase + wr * 128 + fi * 16 + (l >> 4) * 4;
        const int4 tiv = *reinterpret_cast<const int4*>(&tgt[ribase]);
        const int tia[4] = {tiv.x, tiv.y, tiv.z, tiv.w};
        #pragma unroll
        for (int q = 0; q < 4; ++q) {
            const int gi = ribase + q;
            const int ti = tia[q];
            #pragma unroll
            for (int fj = 0; fj < 4; ++fj) {
                const float s  = acc[fi][fj][q];
                const float pc = fmaxf(s, 1e-10f);
                const float e  = __expf(TEMP_INV * pc);
                if (ti != tj[fj]) {
                    denc[fj] += e;
                } else if (gi != jc[fj]) {
                    posc[fj] += pc;
                }
            }
        }
    }

    // Lanes sharing a column differ in bits 4-5.
    #pragma unroll
    for (int fj = 0; fj < 4; ++fj) {
        #pragma unroll
        for (int off = 16; off < 64; off <<= 1) {
            denc[fj] += __shfl_xor(denc[fj], off, 64);
            posc[fj] += __shfl_xor(posc[fj], off, 64);
        }
        if (l < 16) {
            atomicAdd(&denw[jc[fj]], denc[fj]);
            atomicAdd(&posw[jc[fj]], posc[fj]);
        }
    }
}

// Single-block finalize: LDS class histogram + per-column loss + direct store.
__global__ __launch_bounds__(1024) void finalize_k(const float* __restrict__ posw,
                                                   const float* __restrict__ denw,
                                                   const int* __restrict__ tgt,
                                                   float* __restrict__ out) {
    __shared__ int hist[128];
    __shared__ float red[16];
    const int tid = threadIdx.x;
    if (tid < 128) hist[tid] = 0;
    __syncthreads();
    const int4 t4 = reinterpret_cast<const int4*>(tgt)[tid];   // 4 targets/thread
    atomicAdd(&hist[t4.x], 1);
    atomicAdd(&hist[t4.y], 1);
    atomicAdd(&hist[t4.z], 1);
    atomicAdd(&hist[t4.w], 1);
    __syncthreads();
    const int ta[4] = {t4.x, t4.y, t4.z, t4.w};
    float v = 0.0f;
    #pragma unroll
    for (int q = 0; q < 4; ++q) {
        const int j = tid * 4 + q;
        const float d = fmaxf(denw[j], 1e-10f);
        const float c = (float)(hist[ta[q]] - 1);
        v += TEMP_INV * posw[j] - c * __logf(d);
    }
    #pragma unroll
    for (int off = 32; off; off >>= 1) v += __shfl_xor(v, off, 64);
    if ((tid & 63) == 0) red[tid >> 6] = v;
    __syncthreads();
    if (tid == 0) {
        float s = 0.0f;
        #pragma unroll
        for (int i = 0; i < 16; ++i) s += red[i];
        out[0] = -s * (1.0f / 4096.0f);
    }
}

extern "C" void kernel_launch(void* const* d_in, const int* in_sizes, int n_in,
                              void* d_out, int out_size, void* d_ws, size_t ws_size,
                              hipStream_t stream) {
    const float* pred = (const float*)d_in[0];
    const int*   tgt  = (const int*)d_in[1];
    float* out = (float*)d_out;

    unsigned short* xn = (unsigned short*)d_ws;                      // 8 MB bf16
    float* posw = (float*)((char*)d_ws + (size_t)NROWS * DIM * 2);
    float* denw = posw + NROWS;

    normalize_k<<<NROWS, 256, 0, stream>>>(pred, xn, posw, denw);

    fused_gram<<<NTB * NTB, 512, 0, stream>>>(xn, tgt, posw, denw);  // 256 blocks

    finalize_k<<<1, 1024, 0, stream>>>(posw, denw, tgt, out);
}